// Round 5
// baseline (740.934 us; speedup 1.0000x reference)
//
#include <hip/hip_runtime.h>
#include <hip/hip_bf16.h>
#include <cstdint>
#include <cstddef>

typedef __hip_bfloat16 bf16;
typedef __bf16 bf16x8 __attribute__((ext_vector_type(8)));
typedef float f32x4 __attribute__((ext_vector_type(4)));
typedef float f32x16 __attribute__((ext_vector_type(16)));

#define DEVFN static __device__ __forceinline__
// Raw barrier (no waitcnt drain). Counted waits are bare volatile asm with NO
// "memory" clobber (a memory clobber makes the compiler re-order/fence and
// re-inserts full drains - the round-1..3 failure). Ordering among the hot-loop
// ops relies on: volatile-asm <-> volatile-asm order, side-effect intrinsics
// (async copy, barrier), and sched_barrier(0) fences per rule #18.
#define SBAR() __builtin_amdgcn_s_barrier()
#define SCHED0() __builtin_amdgcn_sched_barrier(0)
#define VMCNT(n) asm volatile("s_waitcnt vmcnt(" #n ")")
#define LGKM(n) asm volatile("s_waitcnt lgkmcnt(" #n ")")

// async global->LDS, 16B per lane. LDS dest must be wave-uniform base + lane*16.
DEVFN void async16(const void* g, void* l) {
  __builtin_amdgcn_global_load_lds(
      (const __attribute__((address_space(1))) uint32_t*)g,
      (__attribute__((address_space(3))) uint32_t*)l, 16, 0, 0);
}

// inline-asm LDS read: 16B -> 4 VGPR. Volatile => program-order among asm ops;
// consumer MFMAs are fenced by LGKM(n)+SCHED0 (rule #18: HW has no DS->VALU
// scoreboard, and the compiler must not hoist MFMA above the counted wait).
DEVFN bf16x8 dsr(const bf16* p) {
  bf16x8 r;
  asm volatile("ds_read_b128 %0, %1"
               : "=v"(r)
               : "v"((const __attribute__((address_space(3))) bf16*)p));
  return r;
}

DEVFN float eluf(float v) { return v > 0.f ? v : expm1f(v); }
DEVFN float softplusf(float x) {
  return x > 0.f ? x + log1pf(expf(-x)) : log1pf(expf(x));
}

// ===========================================================================
// 256x256 pipelined GEMM core, 32x32x16 MFMA. 8 waves = 2M x 4N, 512 thr.
// BK=64 = 4 kk-slices of 16. Per wave: acc[4][2] f32x16 (128 AGPR), output
// 128x64. Per phase: 8 MFMA + 6 ds_read_b128 (frags for the NEXT kk).
//
// LDS (bf16 elems, 2 buffers x 32768): buffer b at b*32768:
//   A k-half h (256 rows x 32 k) at  h*8192
//   B k-half h                   at  16384 + h*8192
// K-HALF split (not row-split): kk0/kk1 read only kh0, kk2/kk3 only kh1 --
// this is what gives the last-staged half >=3 phases to land under counted
// vmcnt (a row-split layout needs ALL halves at the kk0 read-ahead => drain).
//
// Swizzle (both-sides involution, rule #21): LDS slot (row, s) holds global
// chunk s ^ (row&3) (16B chunks, 4/row). Staged by pre-swizzling the GLOBAL
// source column (LDS dest of global_load_lds is linear); ds_read applies the
// same XOR. Read pattern: 8 lanes per 4-bank group, distinct rows =>
// conflict-free (verified 0 in rounds 0-4 with the same scheme).
//
// PIPELINE (phase p of tile t; fA/fB frag sets alternate):
//   [6 dsr: frags(kk_next)] [lgkmcnt(6) -> frags(kk_cur) ready]
//   [stage 1 half (2 async16)] [s_barrier] [sched_barrier]
//   [setprio1; 8 MFMA(kk_cur); setprio0] [vmcnt(4)] [s_barrier] [sched_barrier]
// Stage slots: P0: B-kh0(t+1), P1: A-kh1(t+1), P2: B-kh1(t+1), P3: A-kh0(t+2).
// vmcnt(4) keeps 2-3 pairs in flight, never drains in the loop (T4).
// Race proof sketch:
//  - read-gating: vmcnt(4) at end of P2(t) leaves {A-kh1(t+1),B-kh1(t+1)} =>
//    kh0(t+1) landed before kk0(t+1) reads at P3(t); kh1(t) landed (vmcnt at
//    P0-end) before kk2 reads; each wave waits its OWN loads BEFORE a barrier
//    that precedes the dependent reads (cross-wave staging made visible).
//  - stage-vs-inflight-read: every stage is issued after LGKM(6), when the only
//    outstanding reads target the OTHER buffer (P0..P2 stage buf(t+1) while
//    reading buf(t); P3 stages buf(t) while reading buf(t+1)).
//  - stage-vs-old-reads: each region's previous-tenant reads complete >=2
//    barrier-separated phases before the overwrite.
// lgkmcnt counts are exact: the loop issues ONLY the 6 asm ds_reads per phase
// (global_load_lds is vmcnt-only; no SMEM/flat ops in the loop body).
// ===========================================================================

struct FragSet {
  bf16x8 a[4];
  bf16x8 b[2];
};

DEVFN void gemm256(const bf16* __restrict__ pA, const bf16* __restrict__ pB,
                   int lda, int ldb, int NT, bf16* lds, int tid, int wm, int wn,
                   int hi, int l31, f32x16 (&acc)[4][2]) {
  const int k2 = l31 & 3;
  const int swe = (hi ^ k2) * 8;        // chunk offset (elems), even kk
  const int swo = ((2 + hi) ^ k2) * 8;  // odd kk
  const int rowA = (wm * 128 + l31) * 32;
  const int rowB = (wn * 64 + l31) * 32;

  auto READ = [&](FragSet& f, int t, int kk) {
    const bf16* base = lds + (t & 1) * 32768 + (kk >> 1) * 8192 +
                       ((kk & 1) ? swo : swe);
    const bf16* A = base + rowA;
    const bf16* B = base + 16384 + rowB;
#pragma unroll
    for (int mf = 0; mf < 4; ++mf) f.a[mf] = dsr(A + mf * 1024);
#pragma unroll
    for (int nf = 0; nf < 2; ++nf) f.b[nf] = dsr(B + nf * 1024);
  };
  // region: 0=A-kh0 1=A-kh1 2=B-kh0 3=B-kh1
  auto STAGE = [&](int t, int reg) {
    bf16* dst = lds + (t & 1) * 32768 + ((reg >> 1) ? 16384 : 0) +
                (reg & 1) * 8192 + tid * 8;
    const bf16* src =
        ((reg >> 1) ? pB : pA) + (size_t)t * 64 + (reg & 1) * 32;
    const int ld = (reg >> 1) ? ldb : lda;
    async16(src, dst);
    async16(src + (size_t)128 * ld, dst + 4096);
  };
  auto MF = [&](const FragSet& f) {
    __builtin_amdgcn_s_setprio(1);
#pragma unroll
    for (int mf = 0; mf < 4; ++mf)
#pragma unroll
      for (int nf = 0; nf < 2; ++nf)
        acc[mf][nf] = __builtin_amdgcn_mfma_f32_32x32x16_bf16(
            f.a[mf], f.b[nf], acc[mf][nf], 0, 0, 0);
    __builtin_amdgcn_s_setprio(0);
  };

  FragSet fA, fB;
  // prologue: tile0 all halves (kh0 oldest) + tile1 A-kh0.  (NT >= 2 assumed)
  STAGE(0, 0); STAGE(0, 2); STAGE(0, 1); STAGE(0, 3);
  STAGE(1, 0);
  VMCNT(6);  // kh0(0) landed; {A-kh1(0), B-kh1(0), A-kh0(1)} in flight
  SBAR();
  SCHED0();
  READ(fA, 0, 0);

  for (int t = 0; t < NT; ++t) {
    const bool n1 = (t + 1 < NT), n2 = (t + 2 < NT);
    // P0: use fA(kk0), read kk1
    READ(fB, t, 1);
    LGKM(6);
    if (n1) STAGE(t + 1, 2);
    SBAR(); SCHED0();
    MF(fA);
    VMCNT(4);
    SBAR(); SCHED0();
    // P1: use fB(kk1), read kk2
    READ(fA, t, 2);
    LGKM(6);
    if (n1) STAGE(t + 1, 1);
    SBAR(); SCHED0();
    MF(fB);
    VMCNT(4);
    SBAR(); SCHED0();
    // P2: use fA(kk2), read kk3
    READ(fB, t, 3);
    LGKM(6);
    if (n1) STAGE(t + 1, 3);
    SBAR(); SCHED0();
    MF(fA);
    VMCNT(4);
    SBAR(); SCHED0();
    // P3: use fB(kk3), read kk0 of t+1
    if (n1) {
      READ(fA, t + 1, 0);
      LGKM(6);
    } else {
      LGKM(0);
    }
    if (n2) STAGE(t + 2, 0);
    SBAR(); SCHED0();
    MF(fB);
    if (n1) { VMCNT(4); }
    SBAR(); SCHED0();
  }
}

// ---------------------------------------------------------------------------
// BK=32 swizzled K-loop (kept for tail_k's bucketed z-head GEMM).
// Uses __syncthreads() deliberately - its drain makes same-buffer reuse safe.
template <int NAH, int NBH, int NFB>
DEVFN void kloop32(const bf16* (&gA)[NAH], const bf16* (&gB)[NBH], bf16* As,
                   bf16* Bs, int tid, const bf16* aBase, const bf16* bBase,
                   int colsel, f32x4 (&acc)[4][NFB], int kiters) {
  for (int kt = 0; kt < kiters; ++kt) {
#pragma unroll
    for (int c = 0; c < NAH; ++c) async16(gA[c], As + c * 2048 + tid * 8);
#pragma unroll
    for (int c = 0; c < NBH; ++c) async16(gB[c], Bs + c * 2048 + tid * 8);
#pragma unroll
    for (int c = 0; c < NAH; ++c) gA[c] += 32;
#pragma unroll
    for (int c = 0; c < NBH; ++c) gB[c] += 32;
    __syncthreads();
    bf16x8 af[4], bfv[NFB];
#pragma unroll
    for (int r = 0; r < 4; ++r) af[r] = *(const bf16x8*)(aBase + r * 512 + colsel);
#pragma unroll
    for (int c = 0; c < NFB; ++c) bfv[c] = *(const bf16x8*)(bBase + c * 512 + colsel);
#pragma unroll
    for (int r = 0; r < 4; ++r)
#pragma unroll
      for (int c = 0; c < NFB; ++c)
        acc[r][c] = __builtin_amdgcn_mfma_f32_16x16x32_bf16(af[r], bfv[c], acc[r][c], 0, 0, 0);
    __syncthreads();
  }
}

DEVFN int swz_scol(int tid) { return (((tid & 3) ^ ((tid >> 3) & 3)) * 8); }
DEVFN int swz_colsel(int quad, int l15) { return ((quad ^ ((l15 >> 1) & 3)) * 8); }

// ---------------------------------------------------------------------------
// prep: all transposes/converts/bias-concat/bucket-bookkeeping in ONE launch
DEVFN void transpose_tile(const float* src, bf16* dst, int R, int C, int bx, int by) {
  __shared__ float tile[32][33];
  const int c0 = bx * 32, r0 = by * 32;
  const int tx = threadIdx.x & 31, ty = threadIdx.x >> 5;
#pragma unroll
  for (int rr = ty; rr < 32; rr += 8)
    tile[rr][tx] = src[(size_t)(r0 + rr) * C + c0 + tx];
  __syncthreads();
#pragma unroll
  for (int rr = ty; rr < 32; rr += 8)
    dst[(size_t)(c0 + rr) * R + r0 + tx] = __float2bfloat16(tile[tx][rr]);
}

__global__ __launch_bounds__(256) void prep_all_k(
    const float* __restrict__ x, bf16* __restrict__ xb,
    const float* __restrict__ yw0, const float* __restrict__ dw0,
    const float* __restrict__ zw0, const float* __restrict__ tw0,
    bf16* __restrict__ BtL1,
    const float* __restrict__ yw1, const float* __restrict__ dw1,
    const float* __restrict__ zw1, bf16* __restrict__ BtL2,
    const float* __restrict__ tw1, bf16* __restrict__ tw1t,
    const float* __restrict__ zhW, bf16* __restrict__ zhWt,
    const float* __restrict__ yb0, const float* __restrict__ db0,
    const float* __restrict__ zb0, const float* __restrict__ tb0,
    const float* __restrict__ yb1, const float* __restrict__ db1,
    const float* __restrict__ zb1,
    float* __restrict__ biasAll, float* __restrict__ r0All,
    float* __restrict__ r1All, float* __restrict__ biasL2,
    const int* __restrict__ t, int* __restrict__ cnt, int* __restrict__ seg,
    int* __restrict__ rank, int* __restrict__ sids) {
  int l = blockIdx.x;
  if (l < 8192) {  // x fp32 -> bf16, 8 elems/thread
    size_t i = ((size_t)l * 256 + threadIdx.x) * 8;
    float4 v0 = *(const float4*)(x + i);
    float4 v1 = *(const float4*)(x + i + 4);
    union { bf16 h[8]; uint4 u; } o;
    o.h[0] = __float2bfloat16(v0.x); o.h[1] = __float2bfloat16(v0.y);
    o.h[2] = __float2bfloat16(v0.z); o.h[3] = __float2bfloat16(v0.w);
    o.h[4] = __float2bfloat16(v1.x); o.h[5] = __float2bfloat16(v1.y);
    o.h[6] = __float2bfloat16(v1.z); o.h[7] = __float2bfloat16(v1.w);
    *(uint4*)(xb + i) = o.u;
    return;
  }
  l -= 8192;
  if (l < 4096) {  // BtL1: {yw0,dw0,zw0[2:],tw0} transposed
    int z = l >> 10, rem = l & 1023, bx = rem & 31, by = rem >> 5;
    const float* src = (z == 0) ? yw0 : (z == 1) ? dw0 : (z == 2) ? zw0 + 2048 : tw0;
    int C = (z == 3) ? 256 : 1024;
    if (bx * 32 < C)
      transpose_tile(src, BtL1 + (size_t)z * 1024 * 1024, 1024, C, bx, by);
    return;
  }
  l -= 4096;
  if (l < 3072) {  // BtL2: {yw1,dw1,zw1} transposed
    int z = l >> 10, rem = l & 1023, bx = rem & 31, by = rem >> 5;
    const float* src = (z == 0) ? yw1 : (z == 1) ? dw1 : zw1;
    transpose_tile(src, BtL2 + (size_t)z * 1024 * 1024, 1024, 1024, bx, by);
    return;
  }
  l -= 3072;
  if (l < 64) {  // tw1t
    transpose_tile(tw1, tw1t, 256, 256, l & 7, l >> 3);
    return;
  }
  l -= 64;
  if (l < 3584) {  // zhWt: 7 x [1024][512] -> [512][1024]
    int z = l >> 9, rem = l & 511, bx = rem & 15, by = rem >> 4;
    transpose_tile(zhW + (size_t)z * 1024 * 512, zhWt + (size_t)z * 512 * 1024,
                   1024, 512, bx, by);
    return;
  }
  l -= 3584;
  if (l < 13) {  // bias / rank-2 concat
    int i = l * 256 + threadIdx.x;
    if (i >= 3328) return;
    float b;
    if (i < 1024) b = yb0[i];
    else if (i < 2048) b = db0[i - 1024];
    else if (i < 3072) b = zb0[i - 2048];
    else b = tb0[i - 3072];
    biasAll[i] = b;
    bool inz = (i >= 2048 && i < 3072);
    r0All[i] = inz ? zw0[i - 2048] : 0.f;
    r1All[i] = inz ? zw0[1024 + (i - 2048)] : 0.f;
    if (i < 3072)
      biasL2[i] = (i < 1024) ? yb1[i] : (i < 2048) ? db1[i - 1024] : zb1[i - 2048];
    return;
  }
  {  // bucket bookkeeping: single block, 256 threads x 64 items
    __shared__ int h[8], sseg[8];
    const int tid = threadIdx.x;
    if (tid < 8) h[tid] = 0;
    __syncthreads();
    const int base = tid * 64;
    int lc[7] = {0, 0, 0, 0, 0, 0, 0};
    for (int i = 0; i < 64; ++i) lc[t[base + i]]++;
    int myoff[7];
#pragma unroll
    for (int k = 0; k < 7; ++k) myoff[k] = atomicAdd(&h[k], lc[k]);
    __syncthreads();
    if (tid == 0) {
      int s = 0;
      for (int k = 0; k < 7; ++k) { sseg[k] = s; s += h[k]; }
      sseg[7] = s;
    }
    __syncthreads();
    if (tid < 7) { cnt[tid] = h[tid]; seg[tid] = sseg[tid]; }
    if (tid == 7) seg[7] = sseg[7];
    int cur[7];
#pragma unroll
    for (int k = 0; k < 7; ++k) cur[k] = sseg[k] + myoff[k];
    for (int i = 0; i < 64; ++i) {
      int b = base + i, k = t[b];
      int r = cur[k]++;
      rank[b] = r;
      sids[r] = b;
    }
  }
}

// ---------------------------------------------------------------------------
// fused layer-1: [16384,1024] x [1024,3328] -> {a1y,a1d,a1z,ht1}
// 256x256 pipelined core; XCD-contiguous m-bands (832 = 8 xcd x 8 m x 13 n).
__global__ __launch_bounds__(512, 1) void gemm_l1_k(
    const bf16* __restrict__ A, const bf16* __restrict__ Bt,
    const float* __restrict__ biasAll, const float* __restrict__ r0All,
    const float* __restrict__ r1All, const float* __restrict__ yv,
    const float* __restrict__ dv, bf16* __restrict__ a1y,
    bf16* __restrict__ a1d, bf16* __restrict__ a1z, bf16* __restrict__ ht1) {
  __shared__ bf16 lds[65536];  // 128 KiB
  const int tid = threadIdx.x, lane = tid & 63, wid = tid >> 6;
  const int wm = wid >> 2, wn = wid & 3, hi = lane >> 5, l31 = lane & 31;
  const int id = blockIdx.x;
  const int xcd = id & 7, lid = id >> 3;             // lid in [0,104)
  const int mt = xcd * 8 + (lid & 7), nt = lid >> 3; // mt<64, nt<13
  const int bm0 = mt * 256, bn0 = nt * 256;
  const int srow = tid >> 2, sg = (((tid & 3) ^ ((tid >> 2) & 3)) * 8);
  const bf16* pA = A + (size_t)(bm0 + srow) * 1024 + sg;
  const bf16* pB = Bt + (size_t)(bn0 + srow) * 1024 + sg;
  f32x16 acc[4][2] = {};
  gemm256(pA, pB, 1024, 1024, 16, lds, tid, wm, wn, hi, l31, acc);

  const int g = nt >> 2;
  bf16* dst = (g == 0) ? a1y : (g == 1) ? a1d : (g == 2) ? a1z : ht1;
  const int ldc = (g == 3) ? 256 : 1024;
  const int colb = bn0 - g * 1024;
  float bvv[2], z0v[2], z1v[2];
#pragma unroll
  for (int nf = 0; nf < 2; ++nf) {
    int gn = bn0 + wn * 64 + nf * 32 + l31;
    bvv[nf] = biasAll[gn]; z0v[nf] = r0All[gn]; z1v[nf] = r1All[gn];
  }
  // 32x32 C layout: col = lane&31, row = (reg&3) + 8*(reg>>2) + 4*(lane>>5)
#pragma unroll
  for (int mf = 0; mf < 4; ++mf) {
#pragma unroll
    for (int rg = 0; rg < 4; ++rg) {
      const int r0 = bm0 + wm * 128 + mf * 32 + rg * 8 + hi * 4;
      const float4 y4 = *(const float4*)(yv + r0);
      const float4 d4 = *(const float4*)(dv + r0);
#pragma unroll
      for (int q = 0; q < 4; ++q) {
        const float yy = (&y4.x)[q], dd = (&d4.x)[q];
        const size_t ro = (size_t)(r0 + q) * ldc + colb + wn * 64;
#pragma unroll
        for (int nf = 0; nf < 2; ++nf) {
          float v = acc[mf][nf][rg * 4 + q] + bvv[nf] + yy * z0v[nf] + dd * z1v[nf];
          dst[ro + nf * 32 + l31] = __float2bfloat16(eluf(v));
        }
      }
    }
  }
}

// fused layer-2 + t-layer-2: blocks [0,768) = y1|d1|z1 (K=1024, XCD bands),
// blocks [768,832) = t1 (K=256). hz rows written permuted via rank[].
__global__ __launch_bounds__(512, 1) void gemm_l2t_k(
    const bf16* __restrict__ a1y, const bf16* __restrict__ a1d,
    const bf16* __restrict__ a1z, const bf16* __restrict__ ht1,
    const bf16* __restrict__ BtL2, const bf16* __restrict__ tw1t,
    const float* __restrict__ biasL2, const float* __restrict__ tb1,
    bf16* __restrict__ hyd, bf16* __restrict__ hzg, bf16* __restrict__ ht2,
    const int* __restrict__ rank) {
  __shared__ bf16 lds[65536];
  const int tid = threadIdx.x, lane = tid & 63, wid = tid >> 6;
  const int wm = wid >> 2, wn = wid & 3, hi = lane >> 5, l31 = lane & 31;
  const int id = blockIdx.x;
  int bm0, bn0, Ka, g;
  const bf16 *Aptr, *Bptr;
  if (id < 768) {
    const int xcd = id & 7, lid = id >> 3;             // lid in [0,96)
    const int mt = xcd * 8 + (lid & 7), nt = lid >> 3; // mt<64, nt<12
    bm0 = mt * 256; bn0 = nt * 256; Ka = 1024;
    g = nt >> 2;
    Aptr = (g == 0) ? a1y : (g == 1) ? a1d : a1z;
    Bptr = BtL2;
  } else {
    const int local = id - 768;  // [0,64)
    bm0 = local * 256; bn0 = 0; Ka = 256;
    g = 3; Aptr = ht1; Bptr = tw1t;
  }
  const int srow = tid >> 2, sg = (((tid & 3) ^ ((tid >> 2) & 3)) * 8);
  const bf16* pA = Aptr + (size_t)(bm0 + srow) * Ka + sg;
  const bf16* pB = Bptr + (size_t)(bn0 + srow) * Ka + sg;
  f32x16 acc[4][2] = {};
  gemm256(pA, pB, Ka, Ka, Ka >> 6, lds, tid, wm, wn, hi, l31, acc);

  const float* bias = (g == 3) ? tb1 : biasL2;
  float bvv[2];
#pragma unroll
  for (int nf = 0; nf < 2; ++nf) bvv[nf] = bias[bn0 + wn * 64 + nf * 32 + l31];
#pragma unroll
  for (int mf = 0; mf < 4; ++mf) {
#pragma unroll
    for (int rg = 0; rg < 4; ++rg) {
      const int r0 = bm0 + wm * 128 + mf * 32 + rg * 8 + hi * 4;
#pragma unroll
      for (int q = 0; q < 4; ++q) {
        const int gm = r0 + q;
        bf16* dst; size_t rowoff;
        if (g == 2) { dst = hzg; rowoff = (size_t)rank[gm] * 1024 + (size_t)(bn0 - 2048); }
        else if (g == 3) { dst = ht2; rowoff = (size_t)gm * 256; }
        else { dst = hyd; rowoff = (size_t)gm * 2048 + bn0; }
#pragma unroll
        for (int nf = 0; nf < 2; ++nf) {
          float v = acc[mf][nf][rg * 4 + q] + bvv[nf];
          dst[rowoff + wn * 64 + nf * 32 + l31] = __float2bfloat16(eluf(v));
        }
      }
    }
  }
}

// ---------------------------------------------------------------------------
// merged tail: z-head bucketed GEMM (blocks < ZB) + y/d heads + t-logits.
#define ZMT 28  // max m-tiles per bucket (covers 3584 rows; mean 2341, +27 sigma)
#define ZB (7 * ZMT * 8)
__global__ __launch_bounds__(256) void tail_k(
    const bf16* __restrict__ hzg, const bf16* __restrict__ zhWt,
    const float* __restrict__ zhb, const int* __restrict__ seg,
    const int* __restrict__ cnts, const int* __restrict__ sids,
    const bf16* __restrict__ hyd, const bf16* __restrict__ ht2,
    const int* __restrict__ t, const float* __restrict__ yhW,
    const float* __restrict__ yhb, const float* __restrict__ dhW,
    const float* __restrict__ dhb, const float* __restrict__ tw2,
    const float* __restrict__ tb2, float* __restrict__ out) {
  __shared__ bf16 As[128 * 32];  // 8 KB
  __shared__ bf16 Bs[64 * 32];   // 4 KB
  const int tid = threadIdx.x, lane = tid & 63, wid = tid >> 6;
  const int wv = wid, quad = lane >> 4, l15 = lane & 15;
  if (blockIdx.x < ZB) {
    const int kb = blockIdx.x / (ZMT * 8);
    const int r = blockIdx.x % (ZMT * 8);
    const int cnt = cnts[kb];
    const int bm0 = (r >> 3) * 128;
    if (bm0 >= cnt) return;
    const int n0 = (r & 7) * 64;
    const int wm = wid >> 1, wn = wid & 1;
    const int base = seg[kb];
    const int sr = tid >> 2, scol = swz_scol(tid);
    const bf16* gA[2];
    const bf16* gB[1];
#pragma unroll
    for (int c = 0; c < 2; ++c) {
      int rr = bm0 + c * 64 + sr;
      if (rr >= cnt) rr = cnt - 1;
      gA[c] = hzg + (size_t)(base + rr) * 1024 + scol;
    }
    gB[0] = zhWt + (size_t)kb * 512 * 1024 + (size_t)(n0 + sr) * 1024 + scol;
    const bf16* aBase = &As[(wm * 64 + l15) * 32];
    const bf16* bBase = &Bs[(wn * 32 + l15) * 32];
    const int colsel = swz_colsel(quad, l15);
    f32x4 acc[4][2] = {};
    kloop32<2, 1, 2>(gA, gB, As, Bs, tid, aBase, bBase, colsel, acc, 32);
    const float* bias = zhb + (size_t)kb * 512;
    float bv[2]; int gnn[2];
#pragma unroll
    for (int c = 0; c < 2; ++c) {
      gnn[c] = n0 + wn * 32 + c * 16 + l15;
      bv[c] = bias[gnn[c]];
    }
#pragma unroll
    for (int r2 = 0; r2 < 4; ++r2)
#pragma unroll
      for (int q = 0; q < 4; ++q) {
        int lm = bm0 + wm * 64 + r2 * 16 + quad * 4 + q;
        if (lm < cnt) {
          int gm = sids[base + lm];
          size_t ob = (size_t)gm * 523 + 11;
#pragma unroll
          for (int c = 0; c < 2; ++c) {
            float v = acc[r2][c][q] + bv[c];
            int n = gnn[c];
            out[ob + n] = (n < 256) ? fminf(fmaxf(v, -100.f), 100.f)
                                    : fminf(softplusf(v) + 0.001f, 100.f);
          }
        }
      }
    return;
  }
  const int hid = blockIdx.x - ZB;
  if (hid < 4096) {  // y/d heads
    const int b = hid * 4 + wv;
    const int tb = t[b];
    const float* yW = yhW + (size_t)tb * 2048;
    const float* dW = dhW + (size_t)tb * 2048;
    float s0 = 0.f, s1 = 0.f, s2 = 0.f, s3 = 0.f;
    for (int i = lane; i < 1024; i += 64) {
      float a = __bfloat162float(hyd[(size_t)b * 2048 + i]);
      float c = __bfloat162float(hyd[(size_t)b * 2048 + 1024 + i]);
      s0 += a * yW[2 * i]; s1 += a * yW[2 * i + 1];
      s2 += c * dW[2 * i]; s3 += c * dW[2 * i + 1];
    }
#pragma unroll
    for (int off = 32; off > 0; off >>= 1) {
      s0 += __shfl_down(s0, off); s1 += __shfl_down(s1, off);
      s2 += __shfl_down(s2, off); s3 += __shfl_down(s3, off);
    }
    if (lane == 0) {
      size_t o = (size_t)b * 523;
      out[o + 7] = fminf(fmaxf(s0 + yhb[tb * 2], -1e6f), 1e6f);
      out[o + 8] = fminf(softplusf(s1 + yhb[tb * 2 + 1]) + 1e-3f, 1e6f);
      out[o + 9] = fminf(fmaxf(s2 + dhb[tb * 2], -1e6f), 1e6f);
      out[o + 10] = fminf(softplusf(s3 + dhb[tb * 2 + 1]) + 1e-3f, 1e6f);
    }
  } else {  // t logits
    const int b = (hid - 4096) * 4 + wv;
    float h[4];
#pragma unroll
    for (int j = 0; j < 4; ++j)
      h[j] = __bfloat162float(ht2[(size_t)b * 256 + lane * 4 + j]);
    float pp[7];
#pragma unroll
    for (int kk = 0; kk < 7; ++kk) {
      float s = 0.f;
#pragma unroll
      for (int j = 0; j < 4; ++j) s += h[j] * tw2[(lane * 4 + j) * 7 + kk];
      pp[kk] = s;
    }
#pragma unroll
    for (int kk = 0; kk < 7; ++kk)
#pragma unroll
      for (int off = 32; off > 0; off >>= 1) pp[kk] += __shfl_down(pp[kk], off);
    if (lane == 0) {
#pragma unroll
      for (int kk = 0; kk < 7; ++kk) {
        float v = eluf(pp[kk] + tb2[kk]);
        out[(size_t)b * 523 + kk] = fminf(fmaxf(v, -10.f), 10.f);
      }
    }
  }
}

// ---------------------------------------------------------------------------
extern "C" void kernel_launch(void* const* d_in, const int* in_sizes, int n_in,
                              void* d_out, int out_size, void* d_ws, size_t ws_size,
                              hipStream_t stream) {
  const float* x   = (const float*)d_in[0];
  const int*   t   = (const int*)d_in[1];
  const float* yv  = (const float*)d_in[2];
  const float* dv  = (const float*)d_in[3];
  const float* tw0 = (const float*)d_in[4];
  const float* tb0 = (const float*)d_in[5];
  const float* tw1 = (const float*)d_in[6];
  const float* tb1 = (const float*)d_in[7];
  const float* tw2 = (const float*)d_in[8];
  const float* tb2 = (const float*)d_in[9];
  const float* yw0 = (const float*)d_in[10];
  const float* yb0 = (const float*)d_in[11];
  const float* yw1 = (const float*)d_in[12];
  const float* yb1 = (const float*)d_in[13];
  const float* yhW = (const float*)d_in[14];
  const float* yhb = (const float*)d_in[15];
  const float* dw0 = (const float*)d_in[16];
  const float* db0 = (const float*)d_in[17];
  const float* dw1 = (const float*)d_in[18];
  const float* db1 = (const float*)d_in[19];
  const float* dhW = (const float*)d_in[20];
  const float* dhb = (const float*)d_in[21];
  const float* zw0 = (const float*)d_in[22];
  const float* zb0 = (const float*)d_in[23];
  const float* zw1 = (const float*)d_in[24];
  const float* zb1 = (const float*)d_in[25];
  const float* zhW = (const float*)d_in[26];
  const float* zhb = (const float*)d_in[27];
  float* out = (float*)d_out;

  const int B = 16384;
  char* p = (char*)d_ws;
  auto take = [&](size_t bytes) {
    char* r = p;
    p += (bytes + 255) & ~(size_t)255;
    return r;
  };
  bf16*  BtL1    = (bf16*)take((size_t)3328 * 1024 * 2);
  bf16*  BtL2    = (bf16*)take((size_t)3072 * 1024 * 2);
  bf16*  tw1t    = (bf16*)take((size_t)256 * 256 * 2);
  bf16*  zhWt    = (bf16*)take((size_t)7 * 512 * 1024 * 2);
  float* biasAll = (float*)take(3328 * 4);
  float* r0All   = (float*)take(3328 * 4);
  float* r1All   = (float*)take(3328 * 4);
  float* biasL2  = (float*)take(3072 * 4);
  int*   cnt     = (int*)take(8 * 4);
  int*   seg     = (int*)take(8 * 4);
  int*   rank    = (int*)take((size_t)B * 4);
  int*   sids    = (int*)take((size_t)B * 4);
  bf16*  xb      = (bf16*)take((size_t)B * 1024 * 2);  // reused as hzg after L1
  bf16*  a1y     = (bf16*)take((size_t)B * 1024 * 2);
  bf16*  a1d     = (bf16*)take((size_t)B * 1024 * 2);
  bf16*  a1z     = (bf16*)take((size_t)B * 1024 * 2);
  bf16*  ht1     = (bf16*)take((size_t)B * 256 * 2);
  bf16*  hyd     = (bf16*)take((size_t)B * 2048 * 2);
  bf16*  ht2     = (bf16*)take((size_t)B * 256 * 2);
  bf16*  hzg     = xb;

  prep_all_k<<<19022, 256, 0, stream>>>(x, xb, yw0, dw0, zw0, tw0, BtL1,
                                        yw1, dw1, zw1, BtL2, tw1, tw1t, zhW, zhWt,
                                        yb0, db0, zb0, tb0, yb1, db1, zb1,
                                        biasAll, r0All, r1All, biasL2,
                                        t, cnt, seg, rank, sids);
  gemm_l1_k<<<832, 512, 0, stream>>>(xb, BtL1, biasAll, r0All, r1All,
                                     yv, dv, a1y, a1d, a1z, ht1);
  gemm_l2t_k<<<832, 512, 0, stream>>>(a1y, a1d, a1z, ht1, BtL2, tw1t,
                                      biasL2, tb1, hyd, hzg, ht2, rank);
  tail_k<<<ZB + 8192, 256, 0, stream>>>(hzg, zhWt, zhb, seg, cnt, sids,
                                        hyd, ht2, t, yhW, yhb, dhW, dhb,
                                        tw2, tb2, out);
}

// Round 6
// 706.642 us; speedup vs baseline: 1.0485x; 1.0485x over previous
//
#include <hip/hip_runtime.h>
#include <hip/hip_bf16.h>
#include <cstdint>
#include <cstddef>

typedef __hip_bfloat16 bf16;
typedef __bf16 bf16x8 __attribute__((ext_vector_type(8)));
typedef float f32x4 __attribute__((ext_vector_type(4)));
typedef float f32x16 __attribute__((ext_vector_type(16)));

#define DEVFN static __device__ __forceinline__
// Raw barrier (no waitcnt drain). Counted waits are bare volatile asm with NO
// "memory" clobber (a memory clobber makes the compiler re-order/fence and
// re-inserts full drains - the round-1..3 failure). Ordering among the hot-loop
// ops relies on: volatile-asm <-> volatile-asm order, side-effect intrinsics
// (async copy, barrier), and sched_barrier(0) fences per rule #18.
#define SBAR() __builtin_amdgcn_s_barrier()
#define SCHED0() __builtin_amdgcn_sched_barrier(0)
#define VMCNT(n) asm volatile("s_waitcnt vmcnt(" #n ")")
#define LGKM(n) asm volatile("s_waitcnt lgkmcnt(" #n ")")

// async global->LDS, 16B per lane. LDS dest must be wave-uniform base + lane*16.
DEVFN void async16(const void* g, void* l) {
  __builtin_amdgcn_global_load_lds(
      (const __attribute__((address_space(1))) uint32_t*)g,
      (__attribute__((address_space(3))) uint32_t*)l, 16, 0, 0);
}

// inline-asm LDS read: 16B -> 4 VGPR. Volatile => program-order among asm ops;
// consumer MFMAs are fenced by LGKM(n)+SCHED0 (rule #18).
DEVFN bf16x8 dsr(const bf16* p) {
  bf16x8 r;
  asm volatile("ds_read_b128 %0, %1"
               : "=v"(r)
               : "v"((const __attribute__((address_space(3))) bf16*)p));
  return r;
}

DEVFN float eluf(float v) { return v > 0.f ? v : expm1f(v); }
DEVFN float softplusf(float x) {
  return x > 0.f ? x + log1pf(expf(-x)) : log1pf(expf(x));
}

// ===========================================================================
// 256x256 pipelined GEMM core, 32x32x16 MFMA. 8 waves = 2M x 4N, 512 thr.
// BK=64 = 4 kk-slices of 16. Per wave: acc[4][2] f32x16 (128 AGPR), output
// 128x64. Per phase: 8 MFMA + 6 ds_read_b128 (frags for the NEXT kk).
//
// LDS (bf16 elems, 2 buffers x 32768): buffer b at b*32768:
//   A k-half h (256 rows x 32 k) at  h*8192
//   B k-half h                   at  16384 + h*8192
// K-HALF split: kk0/kk1 read only kh0, kk2/kk3 only kh1 -- gives the
// last-staged half >=3 phases to land under counted vmcnt.
//
// Swizzle (both-sides involution, rule #21): LDS slot (row, s) holds global
// chunk s ^ ((row>>1)&3)  (16B chunks, 4/row). KEY IS (row>>1)&3, NOT row&3:
// b128 is serviced 8 lanes/cycle; lane's 4-bank group = (row&1)*16 + slot*4.
// With key=row&3 (round-5 bug) octet lanes {0,4},{1,5},{2,6},{3,7} collide
// (3.07e7 conflicts, +12cyc/read). With key=(row>>1)&3, octet slots
// {0,0,1,1,2,2,3,3} x parity {0,1,...} cover all 8 groups -> conflict-free.
// Key invariant under wm*128/wn*64/mf*32 row offsets (all ==0 mod 4 after >>1).
// Staged by pre-swizzling the GLOBAL source col (LDS dest of global_load_lds
// is linear); ds_read applies the same XOR.
//
// PIPELINE (phase p of tile t; fA/fB frag sets alternate):
//   [6 dsr: frags(kk_next)] [lgkmcnt(6) -> frags(kk_cur) ready]
//   [stage 1 half (2 async16)] [s_barrier] [sched_barrier]
//   [setprio1; 8 MFMA(kk_cur); setprio0] [vmcnt(4)] [s_barrier] [sched_barrier]
// Stage slots: P0: B-kh0(t+1), P1: A-kh1(t+1), P2: B-kh1(t+1), P3: A-kh0(t+2).
// vmcnt(4) keeps 2-3 pairs in flight, never drains in the loop (T4).
// Race proof: see round-5 notes; unchanged (read-gating via vmcnt(4)+barrier;
// stages always target the buffer not being read; overwrites >=2 barrier-
// separated phases after the previous tenant's last read).
// lgkmcnt counts are exact: only the 6 asm ds_reads per phase touch lgkm.
// ===========================================================================

struct FragSet {
  bf16x8 a[4];
  bf16x8 b[2];
};

DEVFN void gemm256(const bf16* __restrict__ pA, const bf16* __restrict__ pB,
                   int lda, int ldb, int NT, bf16* lds, int tid, int wm, int wn,
                   int hi, int l31, f32x16 (&acc)[4][2]) {
  const int k2 = (l31 >> 1) & 3;        // swizzle key (conflict-free octets)
  const int swe = (hi ^ k2) * 8;        // chunk offset (elems), even kk
  const int swo = ((2 + hi) ^ k2) * 8;  // odd kk
  const int rowA = (wm * 128 + l31) * 32;
  const int rowB = (wn * 64 + l31) * 32;

  auto READ = [&](FragSet& f, int t, int kk) {
    const bf16* base = lds + (t & 1) * 32768 + (kk >> 1) * 8192 +
                       ((kk & 1) ? swo : swe);
    const bf16* A = base + rowA;
    const bf16* B = base + 16384 + rowB;
#pragma unroll
    for (int mf = 0; mf < 4; ++mf) f.a[mf] = dsr(A + mf * 1024);
#pragma unroll
    for (int nf = 0; nf < 2; ++nf) f.b[nf] = dsr(B + nf * 1024);
  };
  // region: 0=A-kh0 1=A-kh1 2=B-kh0 3=B-kh1
  auto STAGE = [&](int t, int reg) {
    bf16* dst = lds + (t & 1) * 32768 + ((reg >> 1) ? 16384 : 0) +
                (reg & 1) * 8192 + tid * 8;
    const bf16* src =
        ((reg >> 1) ? pB : pA) + (size_t)t * 64 + (reg & 1) * 32;
    const int ld = (reg >> 1) ? ldb : lda;
    async16(src, dst);
    async16(src + (size_t)128 * ld, dst + 4096);
  };
  auto MF = [&](const FragSet& f) {
    __builtin_amdgcn_s_setprio(1);
#pragma unroll
    for (int mf = 0; mf < 4; ++mf)
#pragma unroll
      for (int nf = 0; nf < 2; ++nf)
        acc[mf][nf] = __builtin_amdgcn_mfma_f32_32x32x16_bf16(
            f.a[mf], f.b[nf], acc[mf][nf], 0, 0, 0);
    __builtin_amdgcn_s_setprio(0);
  };

  FragSet fA, fB;
  // prologue: tile0 all halves (kh0 oldest) + tile1 A-kh0.  (NT >= 2 assumed)
  STAGE(0, 0); STAGE(0, 2); STAGE(0, 1); STAGE(0, 3);
  STAGE(1, 0);
  VMCNT(6);  // kh0(0) landed; {A-kh1(0), B-kh1(0), A-kh0(1)} in flight
  SBAR();
  SCHED0();
  READ(fA, 0, 0);

  for (int t = 0; t < NT; ++t) {
    const bool n1 = (t + 1 < NT), n2 = (t + 2 < NT);
    // P0: use fA(kk0), read kk1
    READ(fB, t, 1);
    LGKM(6);
    if (n1) STAGE(t + 1, 2);
    SBAR(); SCHED0();
    MF(fA);
    VMCNT(4);
    SBAR(); SCHED0();
    // P1: use fB(kk1), read kk2
    READ(fA, t, 2);
    LGKM(6);
    if (n1) STAGE(t + 1, 1);
    SBAR(); SCHED0();
    MF(fB);
    VMCNT(4);
    SBAR(); SCHED0();
    // P2: use fA(kk2), read kk3
    READ(fB, t, 3);
    LGKM(6);
    if (n1) STAGE(t + 1, 3);
    SBAR(); SCHED0();
    MF(fA);
    VMCNT(4);
    SBAR(); SCHED0();
    // P3: use fB(kk3), read kk0 of t+1
    if (n1) {
      READ(fA, t + 1, 0);
      LGKM(6);
    } else {
      LGKM(0);
    }
    if (n2) STAGE(t + 2, 0);
    SBAR(); SCHED0();
    MF(fB);
    if (n1) { VMCNT(4); }
    SBAR(); SCHED0();
  }
}

// ---------------------------------------------------------------------------
// BK=32 swizzled K-loop (kept for tail_k's bucketed z-head GEMM).
// Uses __syncthreads() deliberately - its drain makes same-buffer reuse safe.
template <int NAH, int NBH, int NFB>
DEVFN void kloop32(const bf16* (&gA)[NAH], const bf16* (&gB)[NBH], bf16* As,
                   bf16* Bs, int tid, const bf16* aBase, const bf16* bBase,
                   int colsel, f32x4 (&acc)[4][NFB], int kiters) {
  for (int kt = 0; kt < kiters; ++kt) {
#pragma unroll
    for (int c = 0; c < NAH; ++c) async16(gA[c], As + c * 2048 + tid * 8);
#pragma unroll
    for (int c = 0; c < NBH; ++c) async16(gB[c], Bs + c * 2048 + tid * 8);
#pragma unroll
    for (int c = 0; c < NAH; ++c) gA[c] += 32;
#pragma unroll
    for (int c = 0; c < NBH; ++c) gB[c] += 32;
    __syncthreads();
    bf16x8 af[4], bfv[NFB];
#pragma unroll
    for (int r = 0; r < 4; ++r) af[r] = *(const bf16x8*)(aBase + r * 512 + colsel);
#pragma unroll
    for (int c = 0; c < NFB; ++c) bfv[c] = *(const bf16x8*)(bBase + c * 512 + colsel);
#pragma unroll
    for (int r = 0; r < 4; ++r)
#pragma unroll
      for (int c = 0; c < NFB; ++c)
        acc[r][c] = __builtin_amdgcn_mfma_f32_16x16x32_bf16(af[r], bfv[c], acc[r][c], 0, 0, 0);
    __syncthreads();
  }
}

DEVFN int swz_scol(int tid) { return (((tid & 3) ^ ((tid >> 3) & 3)) * 8); }
DEVFN int swz_colsel(int quad, int l15) { return ((quad ^ ((l15 >> 1) & 3)) * 8); }

// ---------------------------------------------------------------------------
// prep: all transposes/converts/bias-concat/bucket-bookkeeping in ONE launch
DEVFN void transpose_tile(const float* src, bf16* dst, int R, int C, int bx, int by) {
  __shared__ float tile[32][33];
  const int c0 = bx * 32, r0 = by * 32;
  const int tx = threadIdx.x & 31, ty = threadIdx.x >> 5;
#pragma unroll
  for (int rr = ty; rr < 32; rr += 8)
    tile[rr][tx] = src[(size_t)(r0 + rr) * C + c0 + tx];
  __syncthreads();
#pragma unroll
  for (int rr = ty; rr < 32; rr += 8)
    dst[(size_t)(c0 + rr) * R + r0 + tx] = __float2bfloat16(tile[tx][rr]);
}

__global__ __launch_bounds__(256) void prep_all_k(
    const float* __restrict__ x, bf16* __restrict__ xb,
    const float* __restrict__ yw0, const float* __restrict__ dw0,
    const float* __restrict__ zw0, const float* __restrict__ tw0,
    bf16* __restrict__ BtL1,
    const float* __restrict__ yw1, const float* __restrict__ dw1,
    const float* __restrict__ zw1, bf16* __restrict__ BtL2,
    const float* __restrict__ tw1, bf16* __restrict__ tw1t,
    const float* __restrict__ zhW, bf16* __restrict__ zhWt,
    const float* __restrict__ yb0, const float* __restrict__ db0,
    const float* __restrict__ zb0, const float* __restrict__ tb0,
    const float* __restrict__ yb1, const float* __restrict__ db1,
    const float* __restrict__ zb1,
    float* __restrict__ biasAll, float* __restrict__ r0All,
    float* __restrict__ r1All, float* __restrict__ biasL2,
    const int* __restrict__ t, int* __restrict__ cnt, int* __restrict__ seg,
    int* __restrict__ rank, int* __restrict__ sids) {
  int l = blockIdx.x;
  if (l < 8192) {  // x fp32 -> bf16, 8 elems/thread
    size_t i = ((size_t)l * 256 + threadIdx.x) * 8;
    float4 v0 = *(const float4*)(x + i);
    float4 v1 = *(const float4*)(x + i + 4);
    union { bf16 h[8]; uint4 u; } o;
    o.h[0] = __float2bfloat16(v0.x); o.h[1] = __float2bfloat16(v0.y);
    o.h[2] = __float2bfloat16(v0.z); o.h[3] = __float2bfloat16(v0.w);
    o.h[4] = __float2bfloat16(v1.x); o.h[5] = __float2bfloat16(v1.y);
    o.h[6] = __float2bfloat16(v1.z); o.h[7] = __float2bfloat16(v1.w);
    *(uint4*)(xb + i) = o.u;
    return;
  }
  l -= 8192;
  if (l < 4096) {  // BtL1: {yw0,dw0,zw0[2:],tw0} transposed
    int z = l >> 10, rem = l & 1023, bx = rem & 31, by = rem >> 5;
    const float* src = (z == 0) ? yw0 : (z == 1) ? dw0 : (z == 2) ? zw0 + 2048 : tw0;
    int C = (z == 3) ? 256 : 1024;
    if (bx * 32 < C)
      transpose_tile(src, BtL1 + (size_t)z * 1024 * 1024, 1024, C, bx, by);
    return;
  }
  l -= 4096;
  if (l < 3072) {  // BtL2: {yw1,dw1,zw1} transposed
    int z = l >> 10, rem = l & 1023, bx = rem & 31, by = rem >> 5;
    const float* src = (z == 0) ? yw1 : (z == 1) ? dw1 : zw1;
    transpose_tile(src, BtL2 + (size_t)z * 1024 * 1024, 1024, 1024, bx, by);
    return;
  }
  l -= 3072;
  if (l < 64) {  // tw1t
    transpose_tile(tw1, tw1t, 256, 256, l & 7, l >> 3);
    return;
  }
  l -= 64;
  if (l < 3584) {  // zhWt: 7 x [1024][512] -> [512][1024]
    int z = l >> 9, rem = l & 511, bx = rem & 15, by = rem >> 4;
    transpose_tile(zhW + (size_t)z * 1024 * 512, zhWt + (size_t)z * 512 * 1024,
                   1024, 512, bx, by);
    return;
  }
  l -= 3584;
  if (l < 13) {  // bias / rank-2 concat
    int i = l * 256 + threadIdx.x;
    if (i >= 3328) return;
    float b;
    if (i < 1024) b = yb0[i];
    else if (i < 2048) b = db0[i - 1024];
    else if (i < 3072) b = zb0[i - 2048];
    else b = tb0[i - 3072];
    biasAll[i] = b;
    bool inz = (i >= 2048 && i < 3072);
    r0All[i] = inz ? zw0[i - 2048] : 0.f;
    r1All[i] = inz ? zw0[1024 + (i - 2048)] : 0.f;
    if (i < 3072)
      biasL2[i] = (i < 1024) ? yb1[i] : (i < 2048) ? db1[i - 1024] : zb1[i - 2048];
    return;
  }
  {  // bucket bookkeeping: single block, 256 threads x 64 items
    __shared__ int h[8], sseg[8];
    const int tid = threadIdx.x;
    if (tid < 8) h[tid] = 0;
    __syncthreads();
    const int base = tid * 64;
    int lc[7] = {0, 0, 0, 0, 0, 0, 0};
    for (int i = 0; i < 64; ++i) lc[t[base + i]]++;
    int myoff[7];
#pragma unroll
    for (int k = 0; k < 7; ++k) myoff[k] = atomicAdd(&h[k], lc[k]);
    __syncthreads();
    if (tid == 0) {
      int s = 0;
      for (int k = 0; k < 7; ++k) { sseg[k] = s; s += h[k]; }
      sseg[7] = s;
    }
    __syncthreads();
    if (tid < 7) { cnt[tid] = h[tid]; seg[tid] = sseg[tid]; }
    if (tid == 7) seg[7] = sseg[7];
    int cur[7];
#pragma unroll
    for (int k = 0; k < 7; ++k) cur[k] = sseg[k] + myoff[k];
    for (int i = 0; i < 64; ++i) {
      int b = base + i, k = t[b];
      int r = cur[k]++;
      rank[b] = r;
      sids[r] = b;
    }
  }
}

// ---------------------------------------------------------------------------
// fused layer-1: [16384,1024] x [1024,3328] -> {a1y,a1d,a1z,ht1}
// 256x256 pipelined core; XCD-contiguous m-bands (832 = 8 xcd x 8 m x 13 n).
__global__ __launch_bounds__(512, 1) void gemm_l1_k(
    const bf16* __restrict__ A, const bf16* __restrict__ Bt,
    const float* __restrict__ biasAll, const float* __restrict__ r0All,
    const float* __restrict__ r1All, const float* __restrict__ yv,
    const float* __restrict__ dv, bf16* __restrict__ a1y,
    bf16* __restrict__ a1d, bf16* __restrict__ a1z, bf16* __restrict__ ht1) {
  __shared__ bf16 lds[65536];  // 128 KiB
  const int tid = threadIdx.x, lane = tid & 63, wid = tid >> 6;
  const int wm = wid >> 2, wn = wid & 3, hi = lane >> 5, l31 = lane & 31;
  const int id = blockIdx.x;
  const int xcd = id & 7, lid = id >> 3;             // lid in [0,104)
  const int mt = xcd * 8 + (lid & 7), nt = lid >> 3; // mt<64, nt<13
  const int bm0 = mt * 256, bn0 = nt * 256;
  // stage: row = tid>>2, LDS slot = tid&3 -> global chunk (tid&3)^((row>>1)&3)
  const int srow = tid >> 2, sg = (((tid & 3) ^ ((tid >> 3) & 3)) * 8);
  const bf16* pA = A + (size_t)(bm0 + srow) * 1024 + sg;
  const bf16* pB = Bt + (size_t)(bn0 + srow) * 1024 + sg;
  f32x16 acc[4][2] = {};
  gemm256(pA, pB, 1024, 1024, 16, lds, tid, wm, wn, hi, l31, acc);

  const int g = nt >> 2;
  bf16* dst = (g == 0) ? a1y : (g == 1) ? a1d : (g == 2) ? a1z : ht1;
  const int ldc = (g == 3) ? 256 : 1024;
  const int colb = bn0 - g * 1024;
  float bvv[2], z0v[2], z1v[2];
#pragma unroll
  for (int nf = 0; nf < 2; ++nf) {
    int gn = bn0 + wn * 64 + nf * 32 + l31;
    bvv[nf] = biasAll[gn]; z0v[nf] = r0All[gn]; z1v[nf] = r1All[gn];
  }
  // 32x32 C layout: col = lane&31, row = (reg&3) + 8*(reg>>2) + 4*(lane>>5)
#pragma unroll
  for (int mf = 0; mf < 4; ++mf) {
#pragma unroll
    for (int rg = 0; rg < 4; ++rg) {
      const int r0 = bm0 + wm * 128 + mf * 32 + rg * 8 + hi * 4;
      const float4 y4 = *(const float4*)(yv + r0);
      const float4 d4 = *(const float4*)(dv + r0);
#pragma unroll
      for (int q = 0; q < 4; ++q) {
        const float yy = (&y4.x)[q], dd = (&d4.x)[q];
        const size_t ro = (size_t)(r0 + q) * ldc + colb + wn * 64;
#pragma unroll
        for (int nf = 0; nf < 2; ++nf) {
          float v = acc[mf][nf][rg * 4 + q] + bvv[nf] + yy * z0v[nf] + dd * z1v[nf];
          dst[ro + nf * 32 + l31] = __float2bfloat16(eluf(v));
        }
      }
    }
  }
}

// fused layer-2 + t-layer-2: blocks [0,768) = y1|d1|z1 (K=1024, XCD bands),
// blocks [768,832) = t1 (K=256). hz rows written permuted via rank[].
__global__ __launch_bounds__(512, 1) void gemm_l2t_k(
    const bf16* __restrict__ a1y, const bf16* __restrict__ a1d,
    const bf16* __restrict__ a1z, const bf16* __restrict__ ht1,
    const bf16* __restrict__ BtL2, const bf16* __restrict__ tw1t,
    const float* __restrict__ biasL2, const float* __restrict__ tb1,
    bf16* __restrict__ hyd, bf16* __restrict__ hzg, bf16* __restrict__ ht2,
    const int* __restrict__ rank) {
  __shared__ bf16 lds[65536];
  const int tid = threadIdx.x, lane = tid & 63, wid = tid >> 6;
  const int wm = wid >> 2, wn = wid & 3, hi = lane >> 5, l31 = lane & 31;
  const int id = blockIdx.x;
  int bm0, bn0, Ka, g;
  const bf16 *Aptr, *Bptr;
  if (id < 768) {
    const int xcd = id & 7, lid = id >> 3;             // lid in [0,96)
    const int mt = xcd * 8 + (lid & 7), nt = lid >> 3; // mt<64, nt<12
    bm0 = mt * 256; bn0 = nt * 256; Ka = 1024;
    g = nt >> 2;
    Aptr = (g == 0) ? a1y : (g == 1) ? a1d : a1z;
    Bptr = BtL2;
  } else {
    const int local = id - 768;  // [0,64)
    bm0 = local * 256; bn0 = 0; Ka = 256;
    g = 3; Aptr = ht1; Bptr = tw1t;
  }
  const int srow = tid >> 2, sg = (((tid & 3) ^ ((tid >> 3) & 3)) * 8);
  const bf16* pA = Aptr + (size_t)(bm0 + srow) * Ka + sg;
  const bf16* pB = Bptr + (size_t)(bn0 + srow) * Ka + sg;
  f32x16 acc[4][2] = {};
  gemm256(pA, pB, Ka, Ka, Ka >> 6, lds, tid, wm, wn, hi, l31, acc);

  const float* bias = (g == 3) ? tb1 : biasL2;
  float bvv[2];
#pragma unroll
  for (int nf = 0; nf < 2; ++nf) bvv[nf] = bias[bn0 + wn * 64 + nf * 32 + l31];
#pragma unroll
  for (int mf = 0; mf < 4; ++mf) {
#pragma unroll
    for (int rg = 0; rg < 4; ++rg) {
      const int r0 = bm0 + wm * 128 + mf * 32 + rg * 8 + hi * 4;
#pragma unroll
      for (int q = 0; q < 4; ++q) {
        const int gm = r0 + q;
        bf16* dst; size_t rowoff;
        if (g == 2) { dst = hzg; rowoff = (size_t)rank[gm] * 1024 + (size_t)(bn0 - 2048); }
        else if (g == 3) { dst = ht2; rowoff = (size_t)gm * 256; }
        else { dst = hyd; rowoff = (size_t)gm * 2048 + bn0; }
#pragma unroll
        for (int nf = 0; nf < 2; ++nf) {
          float v = acc[mf][nf][rg * 4 + q] + bvv[nf];
          dst[rowoff + wn * 64 + nf * 32 + l31] = __float2bfloat16(eluf(v));
        }
      }
    }
  }
}

// ---------------------------------------------------------------------------
// merged tail: z-head bucketed GEMM (blocks < ZB) + y/d heads + t-logits.
#define ZMT 28  // max m-tiles per bucket (covers 3584 rows; mean 2341, +27 sigma)
#define ZB (7 * ZMT * 8)
__global__ __launch_bounds__(256) void tail_k(
    const bf16* __restrict__ hzg, const bf16* __restrict__ zhWt,
    const float* __restrict__ zhb, const int* __restrict__ seg,
    const int* __restrict__ cnts, const int* __restrict__ sids,
    const bf16* __restrict__ hyd, const bf16* __restrict__ ht2,
    const int* __restrict__ t, const float* __restrict__ yhW,
    const float* __restrict__ yhb, const float* __restrict__ dhW,
    const float* __restrict__ dhb, const float* __restrict__ tw2,
    const float* __restrict__ tb2, float* __restrict__ out) {
  __shared__ bf16 As[128 * 32];  // 8 KB
  __shared__ bf16 Bs[64 * 32];   // 4 KB
  const int tid = threadIdx.x, lane = tid & 63, wid = tid >> 6;
  const int wv = wid, quad = lane >> 4, l15 = lane & 15;
  if (blockIdx.x < ZB) {
    const int kb = blockIdx.x / (ZMT * 8);
    const int r = blockIdx.x % (ZMT * 8);
    const int cnt = cnts[kb];
    const int bm0 = (r >> 3) * 128;
    if (bm0 >= cnt) return;
    const int n0 = (r & 7) * 64;
    const int wm = wid >> 1, wn = wid & 1;
    const int base = seg[kb];
    const int sr = tid >> 2, scol = swz_scol(tid);
    const bf16* gA[2];
    const bf16* gB[1];
#pragma unroll
    for (int c = 0; c < 2; ++c) {
      int rr = bm0 + c * 64 + sr;
      if (rr >= cnt) rr = cnt - 1;
      gA[c] = hzg + (size_t)(base + rr) * 1024 + scol;
    }
    gB[0] = zhWt + (size_t)kb * 512 * 1024 + (size_t)(n0 + sr) * 1024 + scol;
    const bf16* aBase = &As[(wm * 64 + l15) * 32];
    const bf16* bBase = &Bs[(wn * 32 + l15) * 32];
    const int colsel = swz_colsel(quad, l15);
    f32x4 acc[4][2] = {};
    kloop32<2, 1, 2>(gA, gB, As, Bs, tid, aBase, bBase, colsel, acc, 32);
    const float* bias = zhb + (size_t)kb * 512;
    float bv[2]; int gnn[2];
#pragma unroll
    for (int c = 0; c < 2; ++c) {
      gnn[c] = n0 + wn * 32 + c * 16 + l15;
      bv[c] = bias[gnn[c]];
    }
#pragma unroll
    for (int r2 = 0; r2 < 4; ++r2)
#pragma unroll
      for (int q = 0; q < 4; ++q) {
        int lm = bm0 + wm * 64 + r2 * 16 + quad * 4 + q;
        if (lm < cnt) {
          int gm = sids[base + lm];
          size_t ob = (size_t)gm * 523 + 11;
#pragma unroll
          for (int c = 0; c < 2; ++c) {
            float v = acc[r2][c][q] + bv[c];
            int n = gnn[c];
            out[ob + n] = (n < 256) ? fminf(fmaxf(v, -100.f), 100.f)
                                    : fminf(softplusf(v) + 0.001f, 100.f);
          }
        }
      }
    return;
  }
  const int hid = blockIdx.x - ZB;
  if (hid < 4096) {  // y/d heads
    const int b = hid * 4 + wv;
    const int tb = t[b];
    const float* yW = yhW + (size_t)tb * 2048;
    const float* dW = dhW + (size_t)tb * 2048;
    float s0 = 0.f, s1 = 0.f, s2 = 0.f, s3 = 0.f;
    for (int i = lane; i < 1024; i += 64) {
      float a = __bfloat162float(hyd[(size_t)b * 2048 + i]);
      float c = __bfloat162float(hyd[(size_t)b * 2048 + 1024 + i]);
      s0 += a * yW[2 * i]; s1 += a * yW[2 * i + 1];
      s2 += c * dW[2 * i]; s3 += c * dW[2 * i + 1];
    }
#pragma unroll
    for (int off = 32; off > 0; off >>= 1) {
      s0 += __shfl_down(s0, off); s1 += __shfl_down(s1, off);
      s2 += __shfl_down(s2, off); s3 += __shfl_down(s3, off);
    }
    if (lane == 0) {
      size_t o = (size_t)b * 523;
      out[o + 7] = fminf(fmaxf(s0 + yhb[tb * 2], -1e6f), 1e6f);
      out[o + 8] = fminf(softplusf(s1 + yhb[tb * 2 + 1]) + 1e-3f, 1e6f);
      out[o + 9] = fminf(fmaxf(s2 + dhb[tb * 2], -1e6f), 1e6f);
      out[o + 10] = fminf(softplusf(s3 + dhb[tb * 2 + 1]) + 1e-3f, 1e6f);
    }
  } else {  // t logits
    const int b = (hid - 4096) * 4 + wv;
    float h[4];
#pragma unroll
    for (int j = 0; j < 4; ++j)
      h[j] = __bfloat162float(ht2[(size_t)b * 256 + lane * 4 + j]);
    float pp[7];
#pragma unroll
    for (int kk = 0; kk < 7; ++kk) {
      float s = 0.f;
#pragma unroll
      for (int j = 0; j < 4; ++j) s += h[j] * tw2[(lane * 4 + j) * 7 + kk];
      pp[kk] = s;
    }
#pragma unroll
    for (int kk = 0; kk < 7; ++kk)
#pragma unroll
      for (int off = 32; off > 0; off >>= 1) pp[kk] += __shfl_down(pp[kk], off);
    if (lane == 0) {
#pragma unroll
      for (int kk = 0; kk < 7; ++kk) {
        float v = eluf(pp[kk] + tb2[kk]);
        out[(size_t)b * 523 + kk] = fminf(fmaxf(v, -10.f), 10.f);
      }
    }
  }
}

// ---------------------------------------------------------------------------
extern "C" void kernel_launch(void* const* d_in, const int* in_sizes, int n_in,
                              void* d_out, int out_size, void* d_ws, size_t ws_size,
                              hipStream_t stream) {
  const float* x   = (const float*)d_in[0];
  const int*   t   = (const int*)d_in[1];
  const float* yv  = (const float*)d_in[2];
  const float* dv  = (const float*)d_in[3];
  const float* tw0 = (const float*)d_in[4];
  const float* tb0 = (const float*)d_in[5];
  const float* tw1 = (const float*)d_in[6];
  const float* tb1 = (const float*)d_in[7];
  const float* tw2 = (const float*)d_in[8];
  const float* tb2 = (const float*)d_in[9];
  const float* yw0 = (const float*)d_in[10];
  const float* yb0 = (const float*)d_in[11];
  const float* yw1 = (const float*)d_in[12];
  const float* yb1 = (const float*)d_in[13];
  const float* yhW = (const float*)d_in[14];
  const float* yhb = (const float*)d_in[15];
  const float* dw0 = (const float*)d_in[16];
  const float* db0 = (const float*)d_in[17];
  const float* dw1 = (const float*)d_in[18];
  const float* db1 = (const float*)d_in[19];
  const float* dhW = (const float*)d_in[20];
  const float* dhb = (const float*)d_in[21];
  const float* zw0 = (const float*)d_in[22];
  const float* zb0 = (const float*)d_in[23];
  const float* zw1 = (const float*)d_in[24];
  const float* zb1 = (const float*)d_in[25];
  const float* zhW = (const float*)d_in[26];
  const float* zhb = (const float*)d_in[27];
  float* out = (float*)d_out;

  const int B = 16384;
  char* p = (char*)d_ws;
  auto take = [&](size_t bytes) {
    char* r = p;
    p += (bytes + 255) & ~(size_t)255;
    return r;
  };
  bf16*  BtL1    = (bf16*)take((size_t)3328 * 1024 * 2);
  bf16*  BtL2    = (bf16*)take((size_t)3072 * 1024 * 2);
  bf16*  tw1t    = (bf16*)take((size_t)256 * 256 * 2);
  bf16*  zhWt    = (bf16*)take((size_t)7 * 512 * 1024 * 2);
  float* biasAll = (float*)take(3328 * 4);
  float* r0All   = (float*)take(3328 * 4);
  float* r1All   = (float*)take(3328 * 4);
  float* biasL2  = (float*)take(3072 * 4);
  int*   cnt     = (int*)take(8 * 4);
  int*   seg     = (int*)take(8 * 4);
  int*   rank    = (int*)take((size_t)B * 4);
  int*   sids    = (int*)take((size_t)B * 4);
  bf16*  xb      = (bf16*)take((size_t)B * 1024 * 2);  // reused as hzg after L1
  bf16*  a1y     = (bf16*)take((size_t)B * 1024 * 2);
  bf16*  a1d     = (bf16*)take((size_t)B * 1024 * 2);
  bf16*  a1z     = (bf16*)take((size_t)B * 1024 * 2);
  bf16*  ht1     = (bf16*)take((size_t)B * 256 * 2);
  bf16*  hyd     = (bf16*)take((size_t)B * 2048 * 2);
  bf16*  ht2     = (bf16*)take((size_t)B * 256 * 2);
  bf16*  hzg     = xb;

  prep_all_k<<<19022, 256, 0, stream>>>(x, xb, yw0, dw0, zw0, tw0, BtL1,
                                        yw1, dw1, zw1, BtL2, tw1, tw1t, zhW, zhWt,
                                        yb0, db0, zb0, tb0, yb1, db1, zb1,
                                        biasAll, r0All, r1All, biasL2,
                                        t, cnt, seg, rank, sids);
  gemm_l1_k<<<832, 512, 0, stream>>>(xb, BtL1, biasAll, r0All, r1All,
                                     yv, dv, a1y, a1d, a1z, ht1);
  gemm_l2t_k<<<832, 512, 0, stream>>>(a1y, a1d, a1z, ht1, BtL2, tw1t,
                                      biasL2, tb1, hyd, hzg, ht2, rank);
  tail_k<<<ZB + 8192, 256, 0, stream>>>(hzg, zhWt, zhb, seg, cnt, sids,
                                        hyd, ht2, t, yhW, yhb, dhW, dhb,
                                        tw2, tb2, out);
}

// Round 7
// 704.849 us; speedup vs baseline: 1.0512x; 1.0025x over previous
//
#include <hip/hip_runtime.h>
#include <hip/hip_bf16.h>
#include <cstdint>
#include <cstddef>

typedef __hip_bfloat16 bf16;
typedef __bf16 bf16x8 __attribute__((ext_vector_type(8)));
typedef float f32x4 __attribute__((ext_vector_type(4)));
typedef float f32x16 __attribute__((ext_vector_type(16)));

#define DEVFN static __device__ __forceinline__
// Raw barrier (no waitcnt drain). Counted waits are bare volatile asm with NO
// "memory" clobber. Ordering in the hot loop relies on volatile-asm program
// order, side-effecting intrinsics (async copy, barrier), and sched_barrier(0)
// fences per rule #18.
#define SBAR() __builtin_amdgcn_s_barrier()
#define SCHED0() __builtin_amdgcn_sched_barrier(0)
#define VMCNT(n) asm volatile("s_waitcnt vmcnt(" #n ")")
#define LGKM(n) asm volatile("s_waitcnt lgkmcnt(" #n ")")

// async global->LDS, 16B per lane. LDS dest must be wave-uniform base + lane*16.
DEVFN void async16(const void* g, void* l) {
  __builtin_amdgcn_global_load_lds(
      (const __attribute__((address_space(1))) uint32_t*)g,
      (__attribute__((address_space(3))) uint32_t*)l, 16, 0, 0);
}

// inline-asm LDS read: 16B -> 4 VGPR. Volatile => program-order among asm ops;
// consumer MFMAs are fenced by LGKM(n)+SCHED0 (rule #18).
DEVFN bf16x8 dsr(const bf16* p) {
  bf16x8 r;
  asm volatile("ds_read_b128 %0, %1"
               : "=v"(r)
               : "v"((const __attribute__((address_space(3))) bf16*)p));
  return r;
}

DEVFN float eluf(float v) { return v > 0.f ? v : expm1f(v); }
DEVFN float softplusf(float x) {
  return x > 0.f ? x + log1pf(expf(-x)) : log1pf(expf(x));
}

// ===========================================================================
// 256x256 pipelined GEMM core, 32x32x16 MFMA. 8 waves = 2M x 4N, 512 thr.
// BK=64 = 4 kk-slices of 16. Per wave: acc[4][2] f32x16 (128 AGPR).
//
// ROUND-7 RESTRUCTURE: ONE barrier per phase (was two). The pre-MFMA barrier
// protected nothing (MFMA reads own-wave regs only) but forced each phase to
// serialize {48-read LDS cohort} + {MFMA} + 2x barrier skew -> measured 2290
// cyc/phase vs ~600 of real work (r6: MfmaUtil 23.7%). Cross-wave hazards
// exist only at stage<->read handoffs; the end-of-phase barrier covers them.
//
// LDS (2 buffers x 32768 elems): buf b at b*32768:
//   A k-half h (256 rows x 32 k) at h*8192; B k-half h at 16384 + h*8192.
// K-half split: kk0/kk1 read kh0; kk2/kk3 read kh1.
//
// Swizzle (both-sides involution, rule #21): LDS slot (row,s) holds global
// chunk s ^ ((row>>1)&3) (16B chunks). Key (row>>1)&3 gives conflict-free
// octets for b128 (r6 fix); staged via pre-swizzled GLOBAL source column.
//
// Phase skeleton (phases P0..P3 per tile t; fA/fB alternate):
//   READ(kk_next, 6x ds_read) ; LGKM(6) [kk_cur frags ready] ; SCHED0 ;
//   [STAGE batch] ; 8 MFMA(kk_cur) ; [VMCNT gate] ; SBAR ; SCHED0
//
// Stage batches (4 loads/thread each):  P0(t): H1(t+1) = {A,B}-kh1(t+1)
//                                       P2(t): H0(t+2) = {A,B}-kh0(t+2)
// Issue->first-read distance: 5 phases (vs 2 in r5/r6) -> covers HBM latency.
// vmcnt gates (per-thread batches of 4):
//   end-P0(t): VMCNT(8)  in-flight allowed = {H0(t+1)@P2(t-1), H1(t+1)@P0(t)}
//              => H1(t)@P0(t-1) landed, gating P1/P2(t) kh1 reads.
//   end-P2(t): VMCNT(8)  allowed = {H1(t+1)@P0(t), H0(t+2)@P2(t)}
//              => H0(t+1)@P2(t-1) landed, gating P3(t) kh0(t+1) reads.
//   tails: t=NT-2 end-P2 -> VMCNT(4); t=NT-1 end-P0 -> VMCNT(0).
// Region-overwrite safety (>=2 lgkm-drained barriers between last read and
// overwrite): H1(t+1)@P0(t) overwrites kh1(t-1)... prev tenant kh1 of same
// buf is tile t-1, last read P2(t-1), drained by readers' LGKM at P3(t-1),
// barrier end-P3(t-1) precedes stage at P0(t). H0(t+2)@P2(t) overwrites
// kh0(t), last read P0(t) (kk1), drained by LGKM at P1(t), barrier end-P1(t)
// precedes stage at P2(t). Every phase has an LGKM before its SBAR, so all
// waves' reads of phase P are drained before the end-P barrier.
// lgkmcnt counts exact: only the 6 asm ds_reads per phase touch lgkm.
// ===========================================================================

struct FragSet {
  bf16x8 a[4];
  bf16x8 b[2];
};

DEVFN void gemm256(const bf16* __restrict__ pA, const bf16* __restrict__ pB,
                   int lda, int ldb, int NT, bf16* lds, int tid, int wm, int wn,
                   int hi, int l31, f32x16 (&acc)[4][2]) {
  const int k2 = (l31 >> 1) & 3;        // swizzle key (conflict-free octets)
  const int swe = (hi ^ k2) * 8;        // chunk offset (elems), even kk
  const int swo = ((2 + hi) ^ k2) * 8;  // odd kk
  const int rowA = (wm * 128 + l31) * 32;
  const int rowB = (wn * 64 + l31) * 32;

  auto READ = [&](FragSet& f, int t, int kk) {
    const bf16* base = lds + (t & 1) * 32768 + (kk >> 1) * 8192 +
                       ((kk & 1) ? swo : swe);
    const bf16* A = base + rowA;
    const bf16* B = base + 16384 + rowB;
#pragma unroll
    for (int mf = 0; mf < 4; ++mf) f.a[mf] = dsr(A + mf * 1024);
#pragma unroll
    for (int nf = 0; nf < 2; ++nf) f.b[nf] = dsr(B + nf * 1024);
  };
  // stage k-half h of tile t for BOTH A and B (4 async16/thread)
  auto STAGE2 = [&](int t, int h) {
    bf16* dstA = lds + (t & 1) * 32768 + h * 8192 + tid * 8;
    const bf16* srcA = pA + (size_t)t * 64 + h * 32;
    async16(srcA, dstA);
    async16(srcA + (size_t)128 * lda, dstA + 4096);
    bf16* dstB = lds + (t & 1) * 32768 + 16384 + h * 8192 + tid * 8;
    const bf16* srcB = pB + (size_t)t * 64 + h * 32;
    async16(srcB, dstB);
    async16(srcB + (size_t)128 * ldb, dstB + 4096);
  };
  auto MF = [&](const FragSet& f) {
    __builtin_amdgcn_s_setprio(1);
#pragma unroll
    for (int mf = 0; mf < 4; ++mf)
#pragma unroll
      for (int nf = 0; nf < 2; ++nf)
        acc[mf][nf] = __builtin_amdgcn_mfma_f32_32x32x16_bf16(
            f.a[mf], f.b[nf], acc[mf][nf], 0, 0, 0);
    __builtin_amdgcn_s_setprio(0);
  };

  FragSet fA, fB;
  // prologue: H0(0), H1(0), H0(1)  (12 loads/thread; NT >= 2 assumed)
  STAGE2(0, 0);
  STAGE2(0, 1);
  STAGE2(1, 0);
  VMCNT(8);  // H0(0) landed
  SBAR();
  SCHED0();
  READ(fA, 0, 0);

  for (int t = 0; t < NT; ++t) {
    const bool n1 = (t + 1 < NT), n2 = (t + 2 < NT);
    // ---- P0: use fA(kk0), read kk1; stage H1(t+1); gate H1(t)
    READ(fB, t, 1);
    LGKM(6);
    SCHED0();
    if (n1) STAGE2(t + 1, 1);
    MF(fA);
    if (n1) { VMCNT(8); } else { VMCNT(0); }
    SBAR();
    SCHED0();
    // ---- P1: use fB(kk1), read kk2
    READ(fA, t, 2);
    LGKM(6);
    SCHED0();
    MF(fB);
    SBAR();
    SCHED0();
    // ---- P2: use fA(kk2), read kk3; stage H0(t+2); gate H0(t+1)
    READ(fB, t, 3);
    LGKM(6);
    SCHED0();
    if (n2) STAGE2(t + 2, 0);
    MF(fA);
    if (n2) { VMCNT(8); } else if (n1) { VMCNT(4); }
    SBAR();
    SCHED0();
    // ---- P3: use fB(kk3), read kk0 of t+1
    if (n1) {
      READ(fA, t + 1, 0);
      LGKM(6);
    } else {
      LGKM(0);
    }
    SCHED0();
    MF(fB);
    SBAR();
    SCHED0();
  }
}

// ---------------------------------------------------------------------------
// BK=32 swizzled K-loop (kept for tail_k's bucketed z-head GEMM).
// Uses __syncthreads() deliberately - its drain makes same-buffer reuse safe.
template <int NAH, int NBH, int NFB>
DEVFN void kloop32(const bf16* (&gA)[NAH], const bf16* (&gB)[NBH], bf16* As,
                   bf16* Bs, int tid, const bf16* aBase, const bf16* bBase,
                   int colsel, f32x4 (&acc)[4][NFB], int kiters) {
  for (int kt = 0; kt < kiters; ++kt) {
#pragma unroll
    for (int c = 0; c < NAH; ++c) async16(gA[c], As + c * 2048 + tid * 8);
#pragma unroll
    for (int c = 0; c < NBH; ++c) async16(gB[c], Bs + c * 2048 + tid * 8);
#pragma unroll
    for (int c = 0; c < NAH; ++c) gA[c] += 32;
#pragma unroll
    for (int c = 0; c < NBH; ++c) gB[c] += 32;
    __syncthreads();
    bf16x8 af[4], bfv[NFB];
#pragma unroll
    for (int r = 0; r < 4; ++r) af[r] = *(const bf16x8*)(aBase + r * 512 + colsel);
#pragma unroll
    for (int c = 0; c < NFB; ++c) bfv[c] = *(const bf16x8*)(bBase + c * 512 + colsel);
#pragma unroll
    for (int r = 0; r < 4; ++r)
#pragma unroll
      for (int c = 0; c < NFB; ++c)
        acc[r][c] = __builtin_amdgcn_mfma_f32_16x16x32_bf16(af[r], bfv[c], acc[r][c], 0, 0, 0);
    __syncthreads();
  }
}

DEVFN int swz_scol(int tid) { return (((tid & 3) ^ ((tid >> 3) & 3)) * 8); }
DEVFN int swz_colsel(int quad, int l15) { return ((quad ^ ((l15 >> 1) & 3)) * 8); }

// ---------------------------------------------------------------------------
// prep: all transposes/converts/bias-concat/bucket-bookkeeping in ONE launch
DEVFN void transpose_tile(const float* src, bf16* dst, int R, int C, int bx, int by) {
  __shared__ float tile[32][33];
  const int c0 = bx * 32, r0 = by * 32;
  const int tx = threadIdx.x & 31, ty = threadIdx.x >> 5;
#pragma unroll
  for (int rr = ty; rr < 32; rr += 8)
    tile[rr][tx] = src[(size_t)(r0 + rr) * C + c0 + tx];
  __syncthreads();
#pragma unroll
  for (int rr = ty; rr < 32; rr += 8)
    dst[(size_t)(c0 + rr) * R + r0 + tx] = __float2bfloat16(tile[tx][rr]);
}

__global__ __launch_bounds__(256) void prep_all_k(
    const float* __restrict__ x, bf16* __restrict__ xb,
    const float* __restrict__ yw0, const float* __restrict__ dw0,
    const float* __restrict__ zw0, const float* __restrict__ tw0,
    bf16* __restrict__ BtL1,
    const float* __restrict__ yw1, const float* __restrict__ dw1,
    const float* __restrict__ zw1, bf16* __restrict__ BtL2,
    const float* __restrict__ tw1, bf16* __restrict__ tw1t,
    const float* __restrict__ zhW, bf16* __restrict__ zhWt,
    const float* __restrict__ yb0, const float* __restrict__ db0,
    const float* __restrict__ zb0, const float* __restrict__ tb0,
    const float* __restrict__ yb1, const float* __restrict__ db1,
    const float* __restrict__ zb1,
    float* __restrict__ biasAll, float* __restrict__ r0All,
    float* __restrict__ r1All, float* __restrict__ biasL2,
    const int* __restrict__ t, int* __restrict__ cnt, int* __restrict__ seg,
    int* __restrict__ rank, int* __restrict__ sids) {
  int l = blockIdx.x;
  if (l < 8192) {  // x fp32 -> bf16, 8 elems/thread
    size_t i = ((size_t)l * 256 + threadIdx.x) * 8;
    float4 v0 = *(const float4*)(x + i);
    float4 v1 = *(const float4*)(x + i + 4);
    union { bf16 h[8]; uint4 u; } o;
    o.h[0] = __float2bfloat16(v0.x); o.h[1] = __float2bfloat16(v0.y);
    o.h[2] = __float2bfloat16(v0.z); o.h[3] = __float2bfloat16(v0.w);
    o.h[4] = __float2bfloat16(v1.x); o.h[5] = __float2bfloat16(v1.y);
    o.h[6] = __float2bfloat16(v1.z); o.h[7] = __float2bfloat16(v1.w);
    *(uint4*)(xb + i) = o.u;
    return;
  }
  l -= 8192;
  if (l < 4096) {  // BtL1: {yw0,dw0,zw0[2:],tw0} transposed
    int z = l >> 10, rem = l & 1023, bx = rem & 31, by = rem >> 5;
    const float* src = (z == 0) ? yw0 : (z == 1) ? dw0 : (z == 2) ? zw0 + 2048 : tw0;
    int C = (z == 3) ? 256 : 1024;
    if (bx * 32 < C)
      transpose_tile(src, BtL1 + (size_t)z * 1024 * 1024, 1024, C, bx, by);
    return;
  }
  l -= 4096;
  if (l < 3072) {  // BtL2: {yw1,dw1,zw1} transposed
    int z = l >> 10, rem = l & 1023, bx = rem & 31, by = rem >> 5;
    const float* src = (z == 0) ? yw1 : (z == 1) ? dw1 : zw1;
    transpose_tile(src, BtL2 + (size_t)z * 1024 * 1024, 1024, 1024, bx, by);
    return;
  }
  l -= 3072;
  if (l < 64) {  // tw1t
    transpose_tile(tw1, tw1t, 256, 256, l & 7, l >> 3);
    return;
  }
  l -= 64;
  if (l < 3584) {  // zhWt: 7 x [1024][512] -> [512][1024]
    int z = l >> 9, rem = l & 511, bx = rem & 15, by = rem >> 4;
    transpose_tile(zhW + (size_t)z * 1024 * 512, zhWt + (size_t)z * 512 * 1024,
                   1024, 512, bx, by);
    return;
  }
  l -= 3584;
  if (l < 13) {  // bias / rank-2 concat
    int i = l * 256 + threadIdx.x;
    if (i >= 3328) return;
    float b;
    if (i < 1024) b = yb0[i];
    else if (i < 2048) b = db0[i - 1024];
    else if (i < 3072) b = zb0[i - 2048];
    else b = tb0[i - 3072];
    biasAll[i] = b;
    bool inz = (i >= 2048 && i < 3072);
    r0All[i] = inz ? zw0[i - 2048] : 0.f;
    r1All[i] = inz ? zw0[1024 + (i - 2048)] : 0.f;
    if (i < 3072)
      biasL2[i] = (i < 1024) ? yb1[i] : (i < 2048) ? db1[i - 1024] : zb1[i - 2048];
    return;
  }
  {  // bucket bookkeeping: single block, 256 threads x 64 items
    __shared__ int h[8], sseg[8];
    const int tid = threadIdx.x;
    if (tid < 8) h[tid] = 0;
    __syncthreads();
    const int base = tid * 64;
    int lc[7] = {0, 0, 0, 0, 0, 0, 0};
    for (int i = 0; i < 64; ++i) lc[t[base + i]]++;
    int myoff[7];
#pragma unroll
    for (int k = 0; k < 7; ++k) myoff[k] = atomicAdd(&h[k], lc[k]);
    __syncthreads();
    if (tid == 0) {
      int s = 0;
      for (int k = 0; k < 7; ++k) { sseg[k] = s; s += h[k]; }
      sseg[7] = s;
    }
    __syncthreads();
    if (tid < 7) { cnt[tid] = h[tid]; seg[tid] = sseg[tid]; }
    if (tid == 7) seg[7] = sseg[7];
    int cur[7];
#pragma unroll
    for (int k = 0; k < 7; ++k) cur[k] = sseg[k] + myoff[k];
    for (int i = 0; i < 64; ++i) {
      int b = base + i, k = t[b];
      int r = cur[k]++;
      rank[b] = r;
      sids[r] = b;
    }
  }
}

// ---------------------------------------------------------------------------
// fused layer-1: [16384,1024] x [1024,3328] -> {a1y,a1d,a1z,ht1}
// 256x256 pipelined core; XCD-contiguous m-bands (832 = 8 xcd x 8 m x 13 n).
__global__ __launch_bounds__(512, 1) void gemm_l1_k(
    const bf16* __restrict__ A, const bf16* __restrict__ Bt,
    const float* __restrict__ biasAll, const float* __restrict__ r0All,
    const float* __restrict__ r1All, const float* __restrict__ yv,
    const float* __restrict__ dv, bf16* __restrict__ a1y,
    bf16* __restrict__ a1d, bf16* __restrict__ a1z, bf16* __restrict__ ht1) {
  __shared__ bf16 lds[65536];  // 128 KiB
  const int tid = threadIdx.x, lane = tid & 63, wid = tid >> 6;
  const int wm = wid >> 2, wn = wid & 3, hi = lane >> 5, l31 = lane & 31;
  const int id = blockIdx.x;
  const int xcd = id & 7, lid = id >> 3;             // lid in [0,104)
  const int mt = xcd * 8 + (lid & 7), nt = lid >> 3; // mt<64, nt<13
  const int bm0 = mt * 256, bn0 = nt * 256;
  // stage: row = tid>>2, LDS slot = tid&3 -> global chunk (tid&3)^((row>>1)&3)
  const int srow = tid >> 2, sg = (((tid & 3) ^ ((tid >> 3) & 3)) * 8);
  const bf16* pA = A + (size_t)(bm0 + srow) * 1024 + sg;
  const bf16* pB = Bt + (size_t)(bn0 + srow) * 1024 + sg;
  f32x16 acc[4][2] = {};
  gemm256(pA, pB, 1024, 1024, 16, lds, tid, wm, wn, hi, l31, acc);

  const int g = nt >> 2;
  bf16* dst = (g == 0) ? a1y : (g == 1) ? a1d : (g == 2) ? a1z : ht1;
  const int ldc = (g == 3) ? 256 : 1024;
  const int colb = bn0 - g * 1024;
  float bvv[2], z0v[2], z1v[2];
#pragma unroll
  for (int nf = 0; nf < 2; ++nf) {
    int gn = bn0 + wn * 64 + nf * 32 + l31;
    bvv[nf] = biasAll[gn]; z0v[nf] = r0All[gn]; z1v[nf] = r1All[gn];
  }
  // 32x32 C layout: col = lane&31, row = (reg&3) + 8*(reg>>2) + 4*(lane>>5)
#pragma unroll
  for (int mf = 0; mf < 4; ++mf) {
#pragma unroll
    for (int rg = 0; rg < 4; ++rg) {
      const int r0 = bm0 + wm * 128 + mf * 32 + rg * 8 + hi * 4;
      const float4 y4 = *(const float4*)(yv + r0);
      const float4 d4 = *(const float4*)(dv + r0);
#pragma unroll
      for (int q = 0; q < 4; ++q) {
        const float yy = (&y4.x)[q], dd = (&d4.x)[q];
        const size_t ro = (size_t)(r0 + q) * ldc + colb + wn * 64;
#pragma unroll
        for (int nf = 0; nf < 2; ++nf) {
          float v = acc[mf][nf][rg * 4 + q] + bvv[nf] + yy * z0v[nf] + dd * z1v[nf];
          dst[ro + nf * 32 + l31] = __float2bfloat16(eluf(v));
        }
      }
    }
  }
}

// fused layer-2 + t-layer-2: blocks [0,768) = y1|d1|z1 (K=1024, XCD bands),
// blocks [768,832) = t1 (K=256). hz rows written permuted via rank[].
__global__ __launch_bounds__(512, 1) void gemm_l2t_k(
    const bf16* __restrict__ a1y, const bf16* __restrict__ a1d,
    const bf16* __restrict__ a1z, const bf16* __restrict__ ht1,
    const bf16* __restrict__ BtL2, const bf16* __restrict__ tw1t,
    const float* __restrict__ biasL2, const float* __restrict__ tb1,
    bf16* __restrict__ hyd, bf16* __restrict__ hzg, bf16* __restrict__ ht2,
    const int* __restrict__ rank) {
  __shared__ bf16 lds[65536];
  const int tid = threadIdx.x, lane = tid & 63, wid = tid >> 6;
  const int wm = wid >> 2, wn = wid & 3, hi = lane >> 5, l31 = lane & 31;
  const int id = blockIdx.x;
  int bm0, bn0, Ka, g;
  const bf16 *Aptr, *Bptr;
  if (id < 768) {
    const int xcd = id & 7, lid = id >> 3;             // lid in [0,96)
    const int mt = xcd * 8 + (lid & 7), nt = lid >> 3; // mt<64, nt<12
    bm0 = mt * 256; bn0 = nt * 256; Ka = 1024;
    g = nt >> 2;
    Aptr = (g == 0) ? a1y : (g == 1) ? a1d : a1z;
    Bptr = BtL2;
  } else {
    const int local = id - 768;  // [0,64)
    bm0 = local * 256; bn0 = 0; Ka = 256;
    g = 3; Aptr = ht1; Bptr = tw1t;
  }
  const int srow = tid >> 2, sg = (((tid & 3) ^ ((tid >> 3) & 3)) * 8);
  const bf16* pA = Aptr + (size_t)(bm0 + srow) * Ka + sg;
  const bf16* pB = Bptr + (size_t)(bn0 + srow) * Ka + sg;
  f32x16 acc[4][2] = {};
  gemm256(pA, pB, Ka, Ka, Ka >> 6, lds, tid, wm, wn, hi, l31, acc);

  const float* bias = (g == 3) ? tb1 : biasL2;
  float bvv[2];
#pragma unroll
  for (int nf = 0; nf < 2; ++nf) bvv[nf] = bias[bn0 + wn * 64 + nf * 32 + l31];
#pragma unroll
  for (int mf = 0; mf < 4; ++mf) {
#pragma unroll
    for (int rg = 0; rg < 4; ++rg) {
      const int r0 = bm0 + wm * 128 + mf * 32 + rg * 8 + hi * 4;
#pragma unroll
      for (int q = 0; q < 4; ++q) {
        const int gm = r0 + q;
        bf16* dst; size_t rowoff;
        if (g == 2) { dst = hzg; rowoff = (size_t)rank[gm] * 1024 + (size_t)(bn0 - 2048); }
        else if (g == 3) { dst = ht2; rowoff = (size_t)gm * 256; }
        else { dst = hyd; rowoff = (size_t)gm * 2048 + bn0; }
#pragma unroll
        for (int nf = 0; nf < 2; ++nf) {
          float v = acc[mf][nf][rg * 4 + q] + bvv[nf];
          dst[rowoff + wn * 64 + nf * 32 + l31] = __float2bfloat16(eluf(v));
        }
      }
    }
  }
}

// ---------------------------------------------------------------------------
// merged tail: z-head bucketed GEMM (blocks < ZB) + y/d heads + t-logits.
#define ZMT 28  // max m-tiles per bucket (covers 3584 rows; mean 2341, +27 sigma)
#define ZB (7 * ZMT * 8)
__global__ __launch_bounds__(256) void tail_k(
    const bf16* __restrict__ hzg, const bf16* __restrict__ zhWt,
    const float* __restrict__ zhb, const int* __restrict__ seg,
    const int* __restrict__ cnts, const int* __restrict__ sids,
    const bf16* __restrict__ hyd, const bf16* __restrict__ ht2,
    const int* __restrict__ t, const float* __restrict__ yhW,
    const float* __restrict__ yhb, const float* __restrict__ dhW,
    const float* __restrict__ dhb, const float* __restrict__ tw2,
    const float* __restrict__ tb2, float* __restrict__ out) {
  __shared__ bf16 As[128 * 32];  // 8 KB
  __shared__ bf16 Bs[64 * 32];   // 4 KB
  const int tid = threadIdx.x, lane = tid & 63, wid = tid >> 6;
  const int wv = wid, quad = lane >> 4, l15 = lane & 15;
  if (blockIdx.x < ZB) {
    const int kb = blockIdx.x / (ZMT * 8);
    const int r = blockIdx.x % (ZMT * 8);
    const int cnt = cnts[kb];
    const int bm0 = (r >> 3) * 128;
    if (bm0 >= cnt) return;
    const int n0 = (r & 7) * 64;
    const int wm = wid >> 1, wn = wid & 1;
    const int base = seg[kb];
    const int sr = tid >> 2, scol = swz_scol(tid);
    const bf16* gA[2];
    const bf16* gB[1];
#pragma unroll
    for (int c = 0; c < 2; ++c) {
      int rr = bm0 + c * 64 + sr;
      if (rr >= cnt) rr = cnt - 1;
      gA[c] = hzg + (size_t)(base + rr) * 1024 + scol;
    }
    gB[0] = zhWt + (size_t)kb * 512 * 1024 + (size_t)(n0 + sr) * 1024 + scol;
    const bf16* aBase = &As[(wm * 64 + l15) * 32];
    const bf16* bBase = &Bs[(wn * 32 + l15) * 32];
    const int colsel = swz_colsel(quad, l15);
    f32x4 acc[4][2] = {};
    kloop32<2, 1, 2>(gA, gB, As, Bs, tid, aBase, bBase, colsel, acc, 32);
    const float* bias = zhb + (size_t)kb * 512;
    float bv[2]; int gnn[2];
#pragma unroll
    for (int c = 0; c < 2; ++c) {
      gnn[c] = n0 + wn * 32 + c * 16 + l15;
      bv[c] = bias[gnn[c]];
    }
#pragma unroll
    for (int r2 = 0; r2 < 4; ++r2)
#pragma unroll
      for (int q = 0; q < 4; ++q) {
        int lm = bm0 + wm * 64 + r2 * 16 + quad * 4 + q;
        if (lm < cnt) {
          int gm = sids[base + lm];
          size_t ob = (size_t)gm * 523 + 11;
#pragma unroll
          for (int c = 0; c < 2; ++c) {
            float v = acc[r2][c][q] + bv[c];
            int n = gnn[c];
            out[ob + n] = (n < 256) ? fminf(fmaxf(v, -100.f), 100.f)
                                    : fminf(softplusf(v) + 0.001f, 100.f);
          }
        }
      }
    return;
  }
  const int hid = blockIdx.x - ZB;
  if (hid < 4096) {  // y/d heads
    const int b = hid * 4 + wv;
    const int tb = t[b];
    const float* yW = yhW + (size_t)tb * 2048;
    const float* dW = dhW + (size_t)tb * 2048;
    float s0 = 0.f, s1 = 0.f, s2 = 0.f, s3 = 0.f;
    for (int i = lane; i < 1024; i += 64) {
      float a = __bfloat162float(hyd[(size_t)b * 2048 + i]);
      float c = __bfloat162float(hyd[(size_t)b * 2048 + 1024 + i]);
      s0 += a * yW[2 * i]; s1 += a * yW[2 * i + 1];
      s2 += c * dW[2 * i]; s3 += c * dW[2 * i + 1];
    }
#pragma unroll
    for (int off = 32; off > 0; off >>= 1) {
      s0 += __shfl_down(s0, off); s1 += __shfl_down(s1, off);
      s2 += __shfl_down(s2, off); s3 += __shfl_down(s3, off);
    }
    if (lane == 0) {
      size_t o = (size_t)b * 523;
      out[o + 7] = fminf(fmaxf(s0 + yhb[tb * 2], -1e6f), 1e6f);
      out[o + 8] = fminf(softplusf(s1 + yhb[tb * 2 + 1]) + 1e-3f, 1e6f);
      out[o + 9] = fminf(fmaxf(s2 + dhb[tb * 2], -1e6f), 1e6f);
      out[o + 10] = fminf(softplusf(s3 + dhb[tb * 2 + 1]) + 1e-3f, 1e6f);
    }
  } else {  // t logits
    const int b = (hid - 4096) * 4 + wv;
    float h[4];
#pragma unroll
    for (int j = 0; j < 4; ++j)
      h[j] = __bfloat162float(ht2[(size_t)b * 256 + lane * 4 + j]);
    float pp[7];
#pragma unroll
    for (int kk = 0; kk < 7; ++kk) {
      float s = 0.f;
#pragma unroll
      for (int j = 0; j < 4; ++j) s += h[j] * tw2[(lane * 4 + j) * 7 + kk];
      pp[kk] = s;
    }
#pragma unroll
    for (int kk = 0; kk < 7; ++kk)
#pragma unroll
      for (int off = 32; off > 0; off >>= 1) pp[kk] += __shfl_down(pp[kk], off);
    if (lane == 0) {
#pragma unroll
      for (int kk = 0; kk < 7; ++kk) {
        float v = eluf(pp[kk] + tb2[kk]);
        out[(size_t)b * 523 + kk] = fminf(fmaxf(v, -10.f), 10.f);
      }
    }
  }
}

// ---------------------------------------------------------------------------
extern "C" void kernel_launch(void* const* d_in, const int* in_sizes, int n_in,
                              void* d_out, int out_size, void* d_ws, size_t ws_size,
                              hipStream_t stream) {
  const float* x   = (const float*)d_in[0];
  const int*   t   = (const int*)d_in[1];
  const float* yv  = (const float*)d_in[2];
  const float* dv  = (const float*)d_in[3];
  const float* tw0 = (const float*)d_in[4];
  const float* tb0 = (const float*)d_in[5];
  const float* tw1 = (const float*)d_in[6];
  const float* tb1 = (const float*)d_in[7];
  const float* tw2 = (const float*)d_in[8];
  const float* tb2 = (const float*)d_in[9];
  const float* yw0 = (const float*)d_in[10];
  const float* yb0 = (const float*)d_in[11];
  const float* yw1 = (const float*)d_in[12];
  const float* yb1 = (const float*)d_in[13];
  const float* yhW = (const float*)d_in[14];
  const float* yhb = (const float*)d_in[15];
  const float* dw0 = (const float*)d_in[16];
  const float* db0 = (const float*)d_in[17];
  const float* dw1 = (const float*)d_in[18];
  const float* db1 = (const float*)d_in[19];
  const float* dhW = (const float*)d_in[20];
  const float* dhb = (const float*)d_in[21];
  const float* zw0 = (const float*)d_in[22];
  const float* zb0 = (const float*)d_in[23];
  const float* zw1 = (const float*)d_in[24];
  const float* zb1 = (const float*)d_in[25];
  const float* zhW = (const float*)d_in[26];
  const float* zhb = (const float*)d_in[27];
  float* out = (float*)d_out;

  const int B = 16384;
  char* p = (char*)d_ws;
  auto take = [&](size_t bytes) {
    char* r = p;
    p += (bytes + 255) & ~(size_t)255;
    return r;
  };
  bf16*  BtL1    = (bf16*)take((size_t)3328 * 1024 * 2);
  bf16*  BtL2    = (bf16*)take((size_t)3072 * 1024 * 2);
  bf16*  tw1t    = (bf16*)take((size_t)256 * 256 * 2);
  bf16*  zhWt    = (bf16*)take((size_t)7 * 512 * 1024 * 2);
  float* biasAll = (float*)take(3328 * 4);
  float* r0All   = (float*)take(3328 * 4);
  float* r1All   = (float*)take(3328 * 4);
  float* biasL2  = (float*)take(3072 * 4);
  int*   cnt     = (int*)take(8 * 4);
  int*   seg     = (int*)take(8 * 4);
  int*   rank    = (int*)take((size_t)B * 4);
  int*   sids    = (int*)take((size_t)B * 4);
  bf16*  xb      = (bf16*)take((size_t)B * 1024 * 2);  // reused as hzg after L1
  bf16*  a1y     = (bf16*)take((size_t)B * 1024 * 2);
  bf16*  a1d     = (bf16*)take((size_t)B * 1024 * 2);
  bf16*  a1z     = (bf16*)take((size_t)B * 1024 * 2);
  bf16*  ht1     = (bf16*)take((size_t)B * 256 * 2);
  bf16*  hyd     = (bf16*)take((size_t)B * 2048 * 2);
  bf16*  ht2     = (bf16*)take((size_t)B * 256 * 2);
  bf16*  hzg     = xb;

  prep_all_k<<<19022, 256, 0, stream>>>(x, xb, yw0, dw0, zw0, tw0, BtL1,
                                        yw1, dw1, zw1, BtL2, tw1, tw1t, zhW, zhWt,
                                        yb0, db0, zb0, tb0, yb1, db1, zb1,
                                        biasAll, r0All, r1All, biasL2,
                                        t, cnt, seg, rank, sids);
  gemm_l1_k<<<832, 512, 0, stream>>>(xb, BtL1, biasAll, r0All, r1All,
                                     yv, dv, a1y, a1d, a1z, ht1);
  gemm_l2t_k<<<832, 512, 0, stream>>>(a1y, a1d, a1z, ht1, BtL2, tw1t,
                                      biasL2, tb1, hyd, hzg, ht2, rank);
  tail_k<<<ZB + 8192, 256, 0, stream>>>(hzg, zhWt, zhb, seg, cnt, sids,
                                        hyd, ht2, t, yhW, yhb, dhW, dhb,
                                        tw2, tb2, out);
}